// Round 7
// baseline (59.340 us; speedup 1.0000x reference)
//
#include <hip/hip_runtime.h>
#include <hip/hip_bf16.h>

#define B_ 2
#define H_ 16
#define S_ 2048
#define D_ 64

typedef __attribute__((ext_vector_type(8))) short bf16x8;
typedef __attribute__((ext_vector_type(8))) unsigned short u16x8;
typedef __attribute__((ext_vector_type(4))) unsigned int u32x4;
typedef __attribute__((ext_vector_type(4))) float f32x4;
typedef unsigned short ushort_t;

#define SCALE 0.18033688011112042f  // (1/sqrt(64)) * log2(e)

__device__ __forceinline__ unsigned short f2bf(float x) {
  unsigned int u = __builtin_bit_cast(unsigned int, x);
  unsigned int r = (u + 0x7FFFu + ((u >> 16) & 1u)) >> 16;
  return (unsigned short)r;
}

__device__ __forceinline__ unsigned int cvt_pk_bf16(float lo, float hi) {
  unsigned int r;
  asm("v_cvt_pk_bf16_f32 %0, %1, %2" : "=v"(r) : "v"(lo), "v"(hi));
  return r;
}

__device__ __forceinline__ float fmax3(float a, float b, float c) {
  return fmaxf(fmaxf(a, b), c);  // clang fuses to v_max3_f32
}

// sigma: LDS row rl holds K row sigma(rl); bit permute (b5 b4 b3 b2 b1 b0) ->
// (b5 b3 b2 b4 b1 b0). Makes QK^T D-layout == PV B-frag order (P stays in reg).
__device__ __forceinline__ int sigma_row(int rl) {
  return (rl & 0x23) | ((rl & 0x0C) << 1) | ((rl & 0x10) >> 2);
}

#define GLL16(gp, lp)                                                          \
  __builtin_amdgcn_global_load_lds(                                            \
      (const __attribute__((address_space(1))) unsigned int*)(gp),             \
      (__attribute__((address_space(3))) unsigned int*)(lp), 16, 0, 0)

// ---------------- prepass: K/V fp32 -> bf16, swizzle + K-row-permute baked --
__global__ void prepack(const float* __restrict__ Kf, const float* __restrict__ Vf,
                        ushort_t* __restrict__ Kg, ushort_t* __restrict__ Vtg) {
  const int blk = blockIdx.x;  // bh*32 + t
  const int tid = threadIdx.x;
  const int bh = blk >> 5, t = blk & 31;
  const float* srcK = Kf + ((size_t)bh * S_ + (size_t)t * 64) * D_;
  const float* srcV = Vf + ((size_t)bh * S_ + (size_t)t * 64) * D_;
  ushort_t* dK = Kg + (size_t)blk * 4096;
  ushort_t* dV = Vtg + (size_t)blk * 4096;
  for (int is = 0; is < 2; ++is) {
    const int e = is * 2048 + tid * 8;
    {  // K with sigma row permute
      const int rl = e >> 6, pos = (e >> 3) & 7, ch = pos ^ (rl & 7);
      const float* sp = srcK + sigma_row(rl) * 64 + ch * 8;
      float4 a = *(const float4*)sp;
      float4 b = *(const float4*)(sp + 4);
      u16x8 w;
      w[0] = f2bf(a.x); w[1] = f2bf(a.y); w[2] = f2bf(a.z); w[3] = f2bf(a.w);
      w[4] = f2bf(b.x); w[5] = f2bf(b.y); w[6] = f2bf(b.z); w[7] = f2bf(b.w);
      *(u16x8*)(dK + e) = w;
    }
    {  // V transposed
      const int d0 = e >> 6, pos = (e >> 3) & 7, ch = pos ^ (d0 & 7);
      u16x8 w;
      for (int i = 0; i < 8; ++i) w[i] = f2bf(srcV[(size_t)(ch * 8 + i) * 64 + d0]);
      *(u16x8*)(dV + e) = w;
    }
  }
}

// ---------------- hot kernel: pipelined swapped-QK^T flash attention --------
// Pipeline: per segment t -> STAGE K(t+2),V(t+1); QK_LOAD(t+1);
//           SM(t) [VALU, overlaps K ds latency]; QK_MMA(t+1); PV(t); barrier.
template <int PRE>
__launch_bounds__(256, 4)
__global__ void attn7(const float* __restrict__ Qf, const float* __restrict__ Kf,
                      const float* __restrict__ Vf, const ushort_t* __restrict__ Kg,
                      const ushort_t* __restrict__ Vtg, float* __restrict__ O) {
  const int bh = blockIdx.x;          // 0..31
  const int qt = 31 - blockIdx.y;     // LPT: longest blocks first
  const int tid = threadIdx.x;
  const int wave = tid >> 6, lane = tid & 63;
  const int col = lane & 15, g = lane >> 4;

  __shared__ __align__(16) ushort_t Kl[3][64][64];  // 24576 B (triple buf)
  __shared__ __align__(16) ushort_t Vt[2][64][64];  // 16384 B (double buf)

  float* Oh = O + (size_t)bh * S_ * D_;

  // ---- Q fragment (one-time): lane holds Q[qrow][32kk+8g+i] ----
  const int qrow = qt * 64 + wave * 16 + col;
  bf16x8 qf[2];
  {
    const float* Qh = Qf + (size_t)bh * S_ * D_;
    for (int kk = 0; kk < 2; ++kk) {
      const float* p = Qh + (size_t)qrow * 64 + kk * 32 + g * 8;
      float4 a = *(const float4*)p;
      float4 b = *(const float4*)(p + 4);
      float v[8] = {a.x, a.y, a.z, a.w, b.x, b.y, b.z, b.w};
      bf16x8 w;
      for (int i = 0; i < 8; ++i) w[i] = (short)f2bf(v[i] * SCALE);
      qf[kk] = w;
    }
  }

  f32x4 acc[4] = {};
  float m_ = -INFINITY, l_ = 0.0f;  // l_ is PER-LANE partial (combined at end)

  const int ch0 = (g ^ (col & 7)) << 3;
  const int ch1 = ((4 | g) ^ (col & 7)) << 3;

  auto STAGE_K = [&](int t, int kb) {
    if (PRE) {
      const ushort_t* kg = Kg + ((size_t)(bh * 32 + t)) * 4096;
      GLL16(kg + tid * 8,        &Kl[kb][0][0] + tid * 8);
      GLL16(kg + 2048 + tid * 8, &Kl[kb][0][0] + 2048 + tid * 8);
    } else {
      const float* Kh = Kf + (size_t)bh * S_ * D_;
      const int rl = tid >> 2;
      const int c0 = (tid & 3) << 4;
      const float* src = Kh + ((size_t)(t * 64 + sigma_row(rl))) * 64 + c0;
      for (int jj = 0; jj < 2; ++jj) {
        float4 x = *(const float4*)(src + jj * 8);
        float4 y = *(const float4*)(src + jj * 8 + 4);
        u16x8 w;
        w[0] = f2bf(x.x); w[1] = f2bf(x.y); w[2] = f2bf(x.z); w[3] = f2bf(x.w);
        w[4] = f2bf(y.x); w[5] = f2bf(y.y); w[6] = f2bf(y.z); w[7] = f2bf(y.w);
        const int ch = (c0 >> 3) + jj;
        *(u16x8*)&Kl[kb][rl][(ch ^ (rl & 7)) << 3] = w;
      }
    }
  };
  auto STAGE_V = [&](int t, int vb) {
    if (PRE) {
      const ushort_t* vg = Vtg + ((size_t)(bh * 32 + t)) * 4096;
      GLL16(vg + tid * 8,        &Vt[vb][0][0] + tid * 8);
      GLL16(vg + 2048 + tid * 8, &Vt[vb][0][0] + 2048 + tid * 8);
    } else {
      const float* Vh = Vf + (size_t)bh * S_ * D_;
      const int c = tid & 63;
      const int r0 = (tid >> 6) << 4;
      const float* src = Vh + ((size_t)(t * 64 + r0)) * 64 + c;
      for (int jj = 0; jj < 2; ++jj) {
        u16x8 w;
        for (int i = 0; i < 8; ++i) w[i] = f2bf(src[(size_t)(jj * 8 + i) * 64]);
        const int ch = (r0 >> 3) + jj;
        *(u16x8*)&Vt[vb][c][(ch ^ (c & 7)) << 3] = w;
      }
    }
  };

  bf16x8 kreg[8];
  auto QK_LOAD = [&](int kb) {
    #pragma unroll
    for (int nt = 0; nt < 4; ++nt) {
      const ushort_t* row = &Kl[kb][nt * 16 + col][0];
      kreg[2 * nt]     = *(const bf16x8*)(row + ch0);
      kreg[2 * nt + 1] = *(const bf16x8*)(row + ch1);
    }
  };
  auto QK_MMA = [&](f32x4 (&sn)[4]) {
    __builtin_amdgcn_s_setprio(1);
    #pragma unroll
    for (int nt = 0; nt < 4; ++nt) {
      f32x4 z = {0.f, 0.f, 0.f, 0.f};
      z = __builtin_amdgcn_mfma_f32_16x16x32_bf16(kreg[2 * nt], qf[0], z, 0, 0, 0);
      sn[nt] = __builtin_amdgcn_mfma_f32_16x16x32_bf16(kreg[2 * nt + 1], qf[1], z, 0, 0, 0);
    }
    __builtin_amdgcn_s_setprio(0);
  };

  auto SM = [&](f32x4 (&s)[4], bool diag, bf16x8& pf0, bf16x8& pf1) {
    if (diag) {
      const int qloc = wave * 16 + col;
      #pragma unroll
      for (int nt = 0; nt < 4; ++nt) {
        const int tau_base = 32 * (nt >> 1) + 4 * (nt & 1) + 8 * g;
        #pragma unroll
        for (int r = 0; r < 4; ++r)
          if (tau_base + r > qloc) s[nt][r] = -INFINITY;
      }
    }
    // max tree (max3-shaped): 16 in-lane values
    float a0 = fmax3(s[0][0], s[0][1], s[0][2]);
    float a1 = fmax3(s[0][3], s[1][0], s[1][1]);
    float a2 = fmax3(s[1][2], s[1][3], s[2][0]);
    float a3 = fmax3(s[2][1], s[2][2], s[2][3]);
    float a4 = fmax3(s[3][0], s[3][1], s[3][2]);
    float pm = fmax3(fmax3(a0, a1, s[3][3]), fmax3(a2, a3, a4), -INFINITY);
    pm = fmaxf(pm, __shfl_xor(pm, 16));
    pm = fmaxf(pm, __shfl_xor(pm, 32));
    float fac = 1.0f;
    if (!__all(pm - m_ <= 8.0f)) {  // defer-max (T13)
      const float mn = fmaxf(m_, pm);
      fac = exp2f(m_ - mn);
      m_ = mn;
      #pragma unroll
      for (int nt = 0; nt < 4; ++nt) acc[nt] *= fac;
    }
    #pragma unroll
    for (int nt = 0; nt < 4; ++nt)
      #pragma unroll
      for (int r = 0; r < 4; ++r) s[nt][r] = exp2f(s[nt][r] - m_);
    float b0 = (s[0][0] + s[0][1]) + (s[0][2] + s[0][3]);
    float b1 = (s[1][0] + s[1][1]) + (s[1][2] + s[1][3]);
    float b2 = (s[2][0] + s[2][1]) + (s[2][2] + s[2][3]);
    float b3 = (s[3][0] + s[3][1]) + (s[3][2] + s[3][3]);
    l_ = l_ * fac + ((b0 + b1) + (b2 + b3));  // per-lane partial, no shfl
    u32x4 t0, t1;
    t0[0] = cvt_pk_bf16(s[0][0], s[0][1]); t0[1] = cvt_pk_bf16(s[0][2], s[0][3]);
    t0[2] = cvt_pk_bf16(s[1][0], s[1][1]); t0[3] = cvt_pk_bf16(s[1][2], s[1][3]);
    t1[0] = cvt_pk_bf16(s[2][0], s[2][1]); t1[1] = cvt_pk_bf16(s[2][2], s[2][3]);
    t1[2] = cvt_pk_bf16(s[3][0], s[3][1]); t1[3] = cvt_pk_bf16(s[3][2], s[3][3]);
    pf0 = __builtin_bit_cast(bf16x8, t0);
    pf1 = __builtin_bit_cast(bf16x8, t1);
  };

  auto PV = [&](int vb, bf16x8 pf0, bf16x8 pf1) {
    __builtin_amdgcn_s_setprio(1);
    #pragma unroll
    for (int nt = 0; nt < 4; ++nt) {
      const ushort_t* row = &Vt[vb][nt * 16 + col][0];
      const bf16x8 vf0 = *(const bf16x8*)(row + ch0);
      const bf16x8 vf1 = *(const bf16x8*)(row + ch1);
      acc[nt] = __builtin_amdgcn_mfma_f32_16x16x32_bf16(vf0, pf0, acc[nt], 0, 0, 0);
      acc[nt] = __builtin_amdgcn_mfma_f32_16x16x32_bf16(vf1, pf1, acc[nt], 0, 0, 0);
    }
    __builtin_amdgcn_s_setprio(0);
  };

  auto BODY = [&](int t, f32x4 (&cur)[4], f32x4 (&nxt)[4]) {
    const bool haveN = (t + 1 <= qt);
    if (t + 2 <= qt) STAGE_K(t + 2, (t + 2) % 3);
    if (haveN) STAGE_V(t + 1, (t + 1) & 1);
    if (haveN) QK_LOAD((t + 1) % 3);
    bf16x8 pf0, pf1;
    SM(cur, t == qt, pf0, pf1);   // VALU chain overlaps kreg ds latency
    if (haveN) QK_MMA(nxt);       // lgkm wait lands here, after SM
    PV(t & 1, pf0, pf1);
    __syncthreads();
  };

  // prologue
  STAGE_K(0, 0);
  STAGE_V(0, 0);
  if (qt >= 1) STAGE_K(1, 1);
  __syncthreads();
  f32x4 sA[4], sB[4];
  QK_LOAD(0);
  QK_MMA(sA);

  int t = 0;
  while (true) {
    BODY(t, sA, sB); if (++t > qt) break;
    BODY(t, sB, sA); if (++t > qt) break;
  }

  // ---- epilogue: combine per-lane l, store O^T[d=nt*16+4g+r][qrow] ----
  float lsum = l_;
  lsum += __shfl_xor(lsum, 16);
  lsum += __shfl_xor(lsum, 32);
  const float inv = 1.0f / lsum;
  float* dst = Oh + (size_t)qrow * 64;
  #pragma unroll
  for (int nt = 0; nt < 4; ++nt) {
    f32x4 v = acc[nt];
    v *= inv;
    *(f32x4*)(dst + nt * 16 + 4 * g) = v;
  }
}

extern "C" void kernel_launch(void* const* d_in, const int* in_sizes, int n_in,
                              void* d_out, int out_size, void* d_ws, size_t ws_size,
                              hipStream_t stream) {
  const float* Q = (const float*)d_in[0];
  const float* K = (const float*)d_in[1];
  const float* V = (const float*)d_in[2];
  float* O = (float*)d_out;
  const size_t NE = (size_t)B_ * H_ * S_ * D_;  // 4194304
  if (ws_size >= 2 * NE * sizeof(ushort_t)) {
    ushort_t* kg = (ushort_t*)d_ws;
    prepack<<<1024, 256, 0, stream>>>(K, V, kg, kg + NE);
    attn7<1><<<dim3(32, 32), 256, 0, stream>>>(Q, K, V, kg, kg + NE, O);
  } else {
    attn7<0><<<dim3(32, 32), 256, 0, stream>>>(Q, K, V, nullptr, nullptr, O);
  }
}